// Round 3
// baseline (475.457 us; speedup 1.0000x reference)
//
#include <hip/hip_runtime.h>

// ---------- problem constants ----------
#define CDIM   768
#define NSEQ   196
#define NVIEW  5
#define BN_TOT 6272      // B*N
#define VSLAB  150528    // N*C = 196*768

typedef __attribute__((ext_vector_type(8))) short short8;  // 8 bf16 (4 VGPRs)
typedef __attribute__((ext_vector_type(4))) float f32x4;

// ---------- helpers ----------
__device__ __forceinline__ float bf_lo(unsigned u) { return __uint_as_float(u << 16); }
__device__ __forceinline__ float bf_hi(unsigned u) { return __uint_as_float(u & 0xffff0000u); }
__device__ __forceinline__ unsigned short f2bf(float f) {
  unsigned u = __float_as_uint(f);
  return (unsigned short)((u + 0x7fffu + ((u >> 16) & 1u)) >> 16);  // RNE
}
__device__ __forceinline__ unsigned pack2(float f0, float f1) {
  return (unsigned)f2bf(f0) | ((unsigned)f2bf(f1) << 16);
}
__device__ __forceinline__ float ftanh(float x) {
  x = fminf(fmaxf(x, -10.f), 10.f);
  float e = __expf(2.f * x);
  return (e - 1.f) / (e + 1.f);
}
__device__ __forceinline__ void async_cp16(const void* g, void* l) {
  __builtin_amdgcn_global_load_lds((const __attribute__((address_space(1))) unsigned*)g,
                                   (__attribute__((address_space(3))) unsigned*)l, 16, 0, 0);
}

// ---------- weight transpose fp32 -> bf16: 7 matrices of 768x768 ----------
// m<5: wvT[v][d][c] = wv[v][c][d]; m==5: w1aT[h][c] = w1[c][h]; m==6: w1bT[h][c] = w1[C+c][h]
__global__ __launch_bounds__(256) void k_tr(const float* __restrict__ wv,
                                            const float* __restrict__ w1,
                                            unsigned short* __restrict__ wvT,
                                            unsigned short* __restrict__ w1aT,
                                            unsigned short* __restrict__ w1bT) {
  __shared__ float tile[32][33];
  const int m = blockIdx.z;
  const float* src;
  unsigned short* dst;
  if (m < NVIEW)      { src = wv + (size_t)m * 589824; dst = wvT + (size_t)m * 589824; }
  else if (m == NVIEW){ src = w1;                      dst = w1aT; }
  else                { src = w1 + 589824;             dst = w1bT; }
  const int tx = threadIdx.x, ty = threadIdx.y;
  const int x0 = blockIdx.x * 32, y0 = blockIdx.y * 32;
#pragma unroll
  for (int i = 0; i < 4; ++i)
    tile[ty + i * 8][tx] = src[(size_t)(y0 + ty + i * 8) * CDIM + x0 + tx];
  __syncthreads();
#pragma unroll
  for (int i = 0; i < 4; ++i)
    dst[(size_t)(x0 + ty + i * 8) * CDIM + y0 + tx] = f2bf(tile[tx][ty + i * 8]);
}

// ---------- c0 = mean over views (fp32 in, bf16 out) ----------
__global__ __launch_bounds__(192) void k_mean(const float* __restrict__ x,
                                              unsigned short* __restrict__ cb) {
  const int bn = blockIdx.x;
  const int b = bn / NSEQ, n = bn % NSEQ;
  const float* xp = x + ((size_t)(b * NVIEW) * NSEQ + n) * CDIM + threadIdx.x * 4;
  float s0 = 0, s1 = 0, s2 = 0, s3 = 0;
#pragma unroll
  for (int v = 0; v < NVIEW; ++v) {
    float4 p = *(const float4*)(xp + (size_t)v * VSLAB);
    s0 += p.x; s1 += p.y; s2 += p.z; s3 += p.w;
  }
  uint2 o;
  o.x = pack2(s0 * 0.2f, s1 * 0.2f);
  o.y = pack2(s2 * 0.2f, s3 * 0.2f);
  *(uint2*)(cb + (size_t)bn * CDIM + threadIdx.x * 4) = o;
}

// ---------- per-view x slice: fp32 -> bf16, [B,N,C] contiguous ----------
__global__ __launch_bounds__(256) void k_cvt(const float* __restrict__ x,
                                             unsigned short* __restrict__ xbv, int v) {
  const int o = blockIdx.x * 1024 + threadIdx.x * 4;     // 147*1024 = 150528 exactly
  const float4 p = *(const float4*)(x + (size_t)(blockIdx.y * NVIEW + v) * VSLAB + o);
  uint2 q; q.x = pack2(p.x, p.y); q.y = pack2(p.z, p.w);
  *(uint2*)(xbv + (size_t)blockIdx.y * VSLAB + o) = q;
}

// ---------- 128x128-tile bf16 MFMA GEMM; A [6272,768], Bt [768,768]; fused dual-B ----------
// grid.x in [0,12): x<6 -> B0/C0 col-tile x ; x>=6 -> B1/C1 col-tile x-6. (grid.x=6: only B0/C0)
__global__ __launch_bounds__(256) void gemm_bt(const unsigned short* __restrict__ A,
                                               const unsigned short* __restrict__ B0,
                                               const unsigned short* __restrict__ B1,
                                               unsigned short* __restrict__ C0,
                                               unsigned short* __restrict__ C1) {
  __shared__ __align__(16) unsigned short ldsA[128 * 32];
  __shared__ __align__(16) unsigned short ldsB[128 * 32];
  const int t = threadIdx.x;
  const int w = t >> 6, lane = t & 63;
  const int lr = lane & 15, lq = lane >> 4;
  const int wm = (w >> 1) * 64, wn = (w & 1) * 64;
  int nt = blockIdx.x;
  const unsigned short* Bt;
  unsigned short* C;
  if (nt < 6) { Bt = B0; C = C0; } else { Bt = B1; C = C1; nt -= 6; }
  const int mt = blockIdx.y;

  const unsigned short* ga0 = A + ((size_t)mt * 128 + (t >> 2)) * CDIM + (t & 3) * 8;
  const unsigned short* ga1 = ga0 + (size_t)64 * CDIM;
  const unsigned short* gb0 = Bt + ((size_t)nt * 128 + (t >> 2)) * CDIM + (t & 3) * 8;
  const unsigned short* gb1 = gb0 + (size_t)64 * CDIM;

  f32x4 acc[4][4] = {};
  for (int k0 = 0; k0 < CDIM; k0 += 32) {
    __syncthreads();  // previous tile's ds_reads done before overwrite
    async_cp16(ga0 + k0, &ldsA[w * 512]);
    async_cp16(ga1 + k0, &ldsA[2048 + w * 512]);
    async_cp16(gb0 + k0, &ldsB[w * 512]);
    async_cp16(gb1 + k0, &ldsB[2048 + w * 512]);
    __syncthreads();  // drains vmcnt before s_barrier
    short8 af[4], bv[4];
#pragma unroll
    for (int i = 0; i < 4; ++i) af[i] = *(const short8*)&ldsA[(wm + i * 16 + lr) * 32 + lq * 8];
#pragma unroll
    for (int j = 0; j < 4; ++j) bv[j] = *(const short8*)&ldsB[(wn + j * 16 + lr) * 32 + lq * 8];
#pragma unroll
    for (int i = 0; i < 4; ++i)
#pragma unroll
      for (int j = 0; j < 4; ++j)
        acc[i][j] = __builtin_amdgcn_mfma_f32_16x16x32_bf16(af[i], bv[j], acc[i][j], 0, 0, 0);
  }
#pragma unroll
  for (int i = 0; i < 4; ++i)
#pragma unroll
    for (int j = 0; j < 4; ++j) {
      const int gc = nt * 128 + wn + j * 16 + lr;
      const int gr = mt * 128 + wm + i * 16 + lq * 4;   // C/D: row=(lane>>4)*4+reg, col=lane&15
#pragma unroll
      for (int r = 0; r < 4; ++r)
        C[(size_t)(gr + r) * CDIM + gc] = f2bf(acc[i][j][r]);
    }
}

// ---------- s[row] = sum_h w2[h]*tanh(xw1[row,h] + cw1[bn,h] + b1[h])  (b2 softmax-invariant)
__global__ __launch_bounds__(256) void k_score(const unsigned short* __restrict__ xw1b,
                                               const unsigned short* __restrict__ cw1b,
                                               const float* __restrict__ b1,
                                               const float* __restrict__ w2,
                                               float* __restrict__ s) {
  const int w = threadIdx.x >> 6, lane = threadIdx.x & 63;
  const int row = blockIdx.x * 4 + w;          // 7840*4 = 31360 exactly
  const int bn = row % BN_TOT;
  const unsigned short* xr = xw1b + (size_t)row * CDIM;
  const unsigned short* cr = cw1b + (size_t)bn * CDIM;
  float acc = 0.f;
#pragma unroll
  for (int j = 0; j < 3; ++j) {
    const int h = lane * 4 + j * 256;
    uint2 xv = *(const uint2*)(xr + h);
    uint2 cv = *(const uint2*)(cr + h);
    float4 bv = *(const float4*)(b1 + h);
    float4 wv = *(const float4*)(w2 + h);
    acc = fmaf(wv.x, ftanh(bf_lo(xv.x) + bf_lo(cv.x) + bv.x), acc);
    acc = fmaf(wv.y, ftanh(bf_hi(xv.x) + bf_hi(cv.x) + bv.y), acc);
    acc = fmaf(wv.z, ftanh(bf_lo(xv.y) + bf_lo(cv.y) + bv.z), acc);
    acc = fmaf(wv.w, ftanh(bf_hi(xv.y) + bf_hi(cv.y) + bv.w), acc);
  }
#pragma unroll
  for (int off = 32; off > 0; off >>= 1) acc += __shfl_down(acc, off);
  if (lane == 0) s[row] = acc;
}

// ---------- softmax over views + weighted sum of proj; last iter: fp32 outputs + entropy ----------
__global__ __launch_bounds__(192) void k_update(const float* __restrict__ s,
                                                const unsigned short* __restrict__ projb,
                                                unsigned short* __restrict__ cb,
                                                float* __restrict__ outc,
                                                float* __restrict__ outr,
                                                int last) {
  const int bn = blockIdx.x;
  float sv[NVIEW];
#pragma unroll
  for (int v = 0; v < NVIEW; ++v) sv[v] = s[v * BN_TOT + bn];
  float m = sv[0];
#pragma unroll
  for (int v = 1; v < NVIEW; ++v) m = fmaxf(m, sv[v]);
  float a[NVIEW], sum = 0.f;
#pragma unroll
  for (int v = 0; v < NVIEW; ++v) { a[v] = __expf(sv[v] - m); sum += a[v]; }
  const float inv = 1.f / sum;
#pragma unroll
  for (int v = 0; v < NVIEW; ++v) a[v] *= inv;

  const int ci = threadIdx.x * 4;
  float r0 = 0, r1 = 0, r2 = 0, r3 = 0;
#pragma unroll
  for (int v = 0; v < NVIEW; ++v) {
    uint2 p = *(const uint2*)(projb + ((size_t)v * BN_TOT + bn) * CDIM + ci);
    r0 = fmaf(a[v], bf_lo(p.x), r0); r1 = fmaf(a[v], bf_hi(p.x), r1);
    r2 = fmaf(a[v], bf_lo(p.y), r2); r3 = fmaf(a[v], bf_hi(p.y), r3);
  }
  uint2 o; o.x = pack2(r0, r1); o.y = pack2(r2, r3);
  *(uint2*)(cb + (size_t)bn * CDIM + ci) = o;
  if (last) {
    float4 of; of.x = r0; of.y = r1; of.z = r2; of.w = r3;
    *(float4*)(outc + (size_t)bn * CDIM + ci) = of;   // fp32 output
    if (threadIdx.x == 0) {
      float ent = 0.f;
#pragma unroll
      for (int v = 0; v < NVIEW; ++v) ent -= a[v] * logf(a[v] + 1e-8f);
      outr[bn] = 1.f - ent * 0.6213349345596119f;     // 1/ln(5), fp32 output
    }
  }
}

extern "C" void kernel_launch(void* const* d_in, const int* in_sizes, int n_in,
                              void* d_out, int out_size, void* d_ws, size_t ws_size,
                              hipStream_t stream) {
  (void)in_sizes; (void)n_in; (void)out_size; (void)ws_size;
  const float* x  = (const float*)d_in[0];   // [B,V,N,C] fp32
  const float* wv = (const float*)d_in[1];   // [V,C,C]
  const float* w1 = (const float*)d_in[2];   // [2C,H]
  const float* b1 = (const float*)d_in[3];   // [H]
  const float* w2 = (const float*)d_in[4];   // [H,1]
  // d_in[5] = b2: uniform shift over views -> softmax-invariant, unused.

  unsigned short* ws   = (unsigned short*)d_ws;          // peak ~118 MB
  unsigned short* wvT  = ws;                             // 2,949,120
  unsigned short* w1aT = ws + 2949120;                   //   589,824
  unsigned short* w1bT = ws + 3538944;                   //   589,824
  unsigned short* xbv  = ws + 4128768;                   // 4,816,896 (per-view slice)
  unsigned short* cw1b = ws + 4128768;                   // aliases xbv (dead by iter loop)
  unsigned short* projb= ws + 8945664;                   // 24,084,480
  unsigned short* xw1b = ws + 33030144;                  // 24,084,480
  unsigned short* cb   = ws + 57114624;                  //  4,816,896
  float*          s    = (float*)(ws + 61931520);        //     31,360 f32

  float* outc = (float*)d_out;                           // c [B,N,C] fp32
  float* outr = outc + 4816896;                          // r [B,N]   fp32

  k_tr<<<dim3(24, 24, 7), dim3(32, 8), 0, stream>>>(wv, w1, wvT, w1aT, w1bT);
  k_mean<<<BN_TOT, 192, 0, stream>>>(x, cb);
  for (int v = 0; v < NVIEW; ++v) {
    k_cvt<<<dim3(147, 32), 256, 0, stream>>>(x, xbv, v);
    // fused: proj_x[v] = x_v @ w_views[v] ; xw1[v] = x_v @ w1[:C]
    gemm_bt<<<dim3(12, 49), 256, 0, stream>>>(xbv, wvT + (size_t)v * 589824, w1aT,
                                              projb + (size_t)v * 4816896,
                                              xw1b + (size_t)v * 4816896);
  }
  for (int it = 0; it < 3; ++it) {
    gemm_bt<<<dim3(6, 49), 256, 0, stream>>>(cb, w1bT, w1bT, cw1b, cw1b);
    k_score<<<7840, 256, 0, stream>>>(xw1b, cw1b, b1, w2, s);
    k_update<<<BN_TOT, 192, 0, stream>>>(s, projb, cb, outc, outr, it == 2);
  }
}

// Round 4
// 405.082 us; speedup vs baseline: 1.1737x; 1.1737x over previous
//
#include <hip/hip_runtime.h>

// ---------- problem constants ----------
#define CDIM   768
#define NSEQ   196
#define NVIEW  5
#define BN_TOT 6272       // B*N
#define SLAB   4816896    // BN_TOT*CDIM (elements of one [BN,C] matrix)
#define WSLAB  589824     // CDIM*CDIM

typedef __attribute__((ext_vector_type(8))) short short8;  // 8 bf16 (4 VGPRs)
typedef __attribute__((ext_vector_type(4))) float f32x4;

// ---------- helpers ----------
__device__ __forceinline__ float bf_lo(unsigned u) { return __uint_as_float(u << 16); }
__device__ __forceinline__ float bf_hi(unsigned u) { return __uint_as_float(u & 0xffff0000u); }
__device__ __forceinline__ unsigned short f2bf(float f) {
  unsigned u = __float_as_uint(f);
  return (unsigned short)((u + 0x7fffu + ((u >> 16) & 1u)) >> 16);  // RNE
}
__device__ __forceinline__ unsigned pack2(float f0, float f1) {
  return (unsigned)f2bf(f0) | ((unsigned)f2bf(f1) << 16);
}
__device__ __forceinline__ float ftanh(float x) {
  x = fminf(fmaxf(x, -10.f), 10.f);
  float e = __expf(2.f * x);
  return (e - 1.f) / (e + 1.f);
}
__device__ __forceinline__ void async_cp16(const void* g, void* l) {
  __builtin_amdgcn_global_load_lds((const __attribute__((address_space(1))) unsigned*)g,
                                   (__attribute__((address_space(3))) unsigned*)l, 16, 0, 0);
}

// ---------- weight transpose fp32 -> bf16: 7 matrices of 768x768 ----------
__global__ __launch_bounds__(256) void k_tr(const float* __restrict__ wv,
                                            const float* __restrict__ w1,
                                            unsigned short* __restrict__ wvT,
                                            unsigned short* __restrict__ w1aT,
                                            unsigned short* __restrict__ w1bT) {
  __shared__ float tile[32][33];
  const int m = blockIdx.z;
  const float* src;
  unsigned short* dst;
  if (m < NVIEW)      { src = wv + (size_t)m * WSLAB; dst = wvT + (size_t)m * WSLAB; }
  else if (m == NVIEW){ src = w1;                     dst = w1aT; }
  else                { src = w1 + WSLAB;             dst = w1bT; }
  const int tx = threadIdx.x, ty = threadIdx.y;
  const int x0 = blockIdx.x * 32, y0 = blockIdx.y * 32;
#pragma unroll
  for (int i = 0; i < 4; ++i)
    tile[ty + i * 8][tx] = src[(size_t)(y0 + ty + i * 8) * CDIM + x0 + tx];
  __syncthreads();
#pragma unroll
  for (int i = 0; i < 4; ++i)
    dst[(size_t)(x0 + ty + i * 8) * CDIM + y0 + tx] = f2bf(tile[tx][ty + i * 8]);
}

// ---------- single pass over x: xb[v][bn][c] = bf16(x), cb = mean over v ----------
__global__ __launch_bounds__(192) void k_cvt_mean(const float* __restrict__ x,
                                                  unsigned short* __restrict__ xb,
                                                  unsigned short* __restrict__ cb) {
  const int bn = blockIdx.x;
  const int b = bn / NSEQ, n = bn % NSEQ;
  const int h = threadIdx.x * 4;
  const float* xp = x + ((size_t)(b * NVIEW) * NSEQ + n) * CDIM + h;
  float s0 = 0, s1 = 0, s2 = 0, s3 = 0;
#pragma unroll
  for (int v = 0; v < NVIEW; ++v) {
    float4 p = *(const float4*)(xp + (size_t)v * (NSEQ * CDIM));
    s0 += p.x; s1 += p.y; s2 += p.z; s3 += p.w;
    uint2 q; q.x = pack2(p.x, p.y); q.y = pack2(p.z, p.w);
    *(uint2*)(xb + ((size_t)v * BN_TOT + bn) * CDIM + h) = q;
  }
  uint2 o;
  o.x = pack2(s0 * 0.2f, s1 * 0.2f);
  o.y = pack2(s2 * 0.2f, s3 * 0.2f);
  *(uint2*)(cb + (size_t)bn * CDIM + h) = o;
}

// ---------- 128x128-tile bf16 MFMA GEMM, Bt [Nout,K] ----------
// MODE 0 (grid 12,49,5): A=P0+z*SLAB; x<6: Bt=P1+z*WSLAB,C=Q0+z*SLAB (proj); x>=6: Bt=P2,C=Q1+z*SLAB (xw1)
// MODE 1 (grid 6,49,6):  z<5: A=P0+z*SLAB,C=Q0+z*SLAB (pw1b); z==5: A=P1,C=Q1 (cw1_0). Bt=P2 (w1bT)
template <int MODE>
__global__ __launch_bounds__(256) void gemm_bt(const unsigned short* __restrict__ P0,
                                               const unsigned short* __restrict__ P1,
                                               const unsigned short* __restrict__ P2,
                                               unsigned short* __restrict__ Q0,
                                               unsigned short* __restrict__ Q1) {
  __shared__ __align__(16) unsigned short ldsA[128 * 32];
  __shared__ __align__(16) unsigned short ldsB[128 * 32];
  const int t = threadIdx.x;
  const int w = t >> 6, lane = t & 63;
  const int lr = lane & 15, lq = lane >> 4;
  const int wm = (w >> 1) * 64, wn = (w & 1) * 64;
  const int mt = blockIdx.y, z = blockIdx.z;
  int nt = blockIdx.x;
  const unsigned short *A, *Bt;
  unsigned short* C;
  if (MODE == 0) {
    A = P0 + (size_t)z * SLAB;
    if (nt < 6) { Bt = P1 + (size_t)z * WSLAB; C = Q0 + (size_t)z * SLAB; }
    else        { Bt = P2;                     C = Q1 + (size_t)z * SLAB; nt -= 6; }
  } else {
    Bt = P2;
    if (z < NVIEW) { A = P0 + (size_t)z * SLAB; C = Q0 + (size_t)z * SLAB; }
    else           { A = P1;                    C = Q1; }
  }

  const unsigned short* ga0 = A + ((size_t)mt * 128 + (t >> 2)) * CDIM + (t & 3) * 8;
  const unsigned short* ga1 = ga0 + (size_t)64 * CDIM;
  const unsigned short* gb0 = Bt + ((size_t)nt * 128 + (t >> 2)) * CDIM + (t & 3) * 8;
  const unsigned short* gb1 = gb0 + (size_t)64 * CDIM;

  f32x4 acc[4][4] = {};
  for (int k0 = 0; k0 < CDIM; k0 += 32) {
    __syncthreads();  // previous tile's ds_reads done before overwrite
    async_cp16(ga0 + k0, &ldsA[w * 512]);
    async_cp16(ga1 + k0, &ldsA[2048 + w * 512]);
    async_cp16(gb0 + k0, &ldsB[w * 512]);
    async_cp16(gb1 + k0, &ldsB[2048 + w * 512]);
    __syncthreads();  // drains vmcnt before s_barrier
    short8 af[4], bv[4];
#pragma unroll
    for (int i = 0; i < 4; ++i) af[i] = *(const short8*)&ldsA[(wm + i * 16 + lr) * 32 + lq * 8];
#pragma unroll
    for (int j = 0; j < 4; ++j) bv[j] = *(const short8*)&ldsB[(wn + j * 16 + lr) * 32 + lq * 8];
#pragma unroll
    for (int i = 0; i < 4; ++i)
#pragma unroll
      for (int j = 0; j < 4; ++j)
        acc[i][j] = __builtin_amdgcn_mfma_f32_16x16x32_bf16(af[i], bv[j], acc[i][j], 0, 0, 0);
  }
#pragma unroll
  for (int i = 0; i < 4; ++i)
#pragma unroll
    for (int j = 0; j < 4; ++j) {
      const int gc = nt * 128 + wn + j * 16 + lr;
      const int gr = mt * 128 + wm + i * 16 + lq * 4;   // C/D: row=(lane>>4)*4+reg, col=lane&15
#pragma unroll
      for (int r = 0; r < 4; ++r)
        C[(size_t)(gr + r) * CDIM + gc] = f2bf(acc[i][j][r]);
    }
}

// ---------- fused iteration: scores -> softmax -> weighted sum ----------
// phase 1: s_v = sum_h w2[h]*tanh(xw1b[v,bn,h] + cw1[bn,h] + b1[h])   (b2 softmax-invariant)
// phase 2: !last: cw1[bn,:] = sum_v a_v * pw[v,bn,:]  (pw = proj@w1b, bf16)
//           last: outc[bn,:] = sum_v a_v * pw[v,bn,:] (pw = projb) fp32; outr = routing score
__global__ __launch_bounds__(192) void k_iter(const unsigned short* __restrict__ xw1b,
                                              unsigned short* __restrict__ cw1,
                                              const unsigned short* __restrict__ pw,
                                              const float* __restrict__ b1,
                                              const float* __restrict__ w2,
                                              float* __restrict__ outc,
                                              float* __restrict__ outr, int last) {
  __shared__ float red[3][NVIEW];
  __shared__ float aa[NVIEW];
  const int bn = blockIdx.x;
  const int t = threadIdx.x, wv_ = t >> 6, lane = t & 63;
  const int h = t * 4;

  uint2 cv = *(const uint2*)(cw1 + (size_t)bn * CDIM + h);
  float4 bv = *(const float4*)(b1 + h);
  float4 w2v = *(const float4*)(w2 + h);
  const float c0 = bf_lo(cv.x) + bv.x, c1 = bf_hi(cv.x) + bv.y;
  const float c2 = bf_lo(cv.y) + bv.z, c3 = bf_hi(cv.y) + bv.w;

  float part[NVIEW];
#pragma unroll
  for (int v = 0; v < NVIEW; ++v) {
    uint2 xv = *(const uint2*)(xw1b + ((size_t)v * BN_TOT + bn) * CDIM + h);
    float p;
    p  = w2v.x * ftanh(bf_lo(xv.x) + c0);
    p  = fmaf(w2v.y, ftanh(bf_hi(xv.x) + c1), p);
    p  = fmaf(w2v.z, ftanh(bf_lo(xv.y) + c2), p);
    p  = fmaf(w2v.w, ftanh(bf_hi(xv.y) + c3), p);
    part[v] = p;
  }
#pragma unroll
  for (int off = 32; off > 0; off >>= 1)
#pragma unroll
    for (int v = 0; v < NVIEW; ++v) part[v] += __shfl_down(part[v], off);
  if (lane == 0)
#pragma unroll
    for (int v = 0; v < NVIEW; ++v) red[wv_][v] = part[v];
  __syncthreads();
  if (t == 0) {
    float s[NVIEW];
#pragma unroll
    for (int v = 0; v < NVIEW; ++v) s[v] = red[0][v] + red[1][v] + red[2][v];
    float m = s[0];
#pragma unroll
    for (int v = 1; v < NVIEW; ++v) m = fmaxf(m, s[v]);
    float a[NVIEW], sum = 0.f;
#pragma unroll
    for (int v = 0; v < NVIEW; ++v) { a[v] = __expf(s[v] - m); sum += a[v]; }
    const float inv = 1.f / sum;
#pragma unroll
    for (int v = 0; v < NVIEW; ++v) { a[v] *= inv; aa[v] = a[v]; }
    if (last) {
      float ent = 0.f;
#pragma unroll
      for (int v = 0; v < NVIEW; ++v) ent -= a[v] * logf(a[v] + 1e-8f);
      outr[bn] = 1.f - ent * 0.6213349345596119f;  // 1/ln(5)
    }
  }
  __syncthreads();

  float a0 = aa[0], a1 = aa[1], a2 = aa[2], a3 = aa[3], a4 = aa[4];
  float r0 = 0, r1 = 0, r2 = 0, r3 = 0;
#pragma unroll
  for (int v = 0; v < NVIEW; ++v) {
    const float av = (v == 0) ? a0 : (v == 1) ? a1 : (v == 2) ? a2 : (v == 3) ? a3 : a4;
    uint2 p = *(const uint2*)(pw + ((size_t)v * BN_TOT + bn) * CDIM + h);
    r0 = fmaf(av, bf_lo(p.x), r0); r1 = fmaf(av, bf_hi(p.x), r1);
    r2 = fmaf(av, bf_lo(p.y), r2); r3 = fmaf(av, bf_hi(p.y), r3);
  }
  if (!last) {
    uint2 o; o.x = pack2(r0, r1); o.y = pack2(r2, r3);
    *(uint2*)(cw1 + (size_t)bn * CDIM + h) = o;
  } else {
    float4 of; of.x = r0; of.y = r1; of.z = r2; of.w = r3;
    *(float4*)(outc + (size_t)bn * CDIM + h) = of;
  }
}

extern "C" void kernel_launch(void* const* d_in, const int* in_sizes, int n_in,
                              void* d_out, int out_size, void* d_ws, size_t ws_size,
                              hipStream_t stream) {
  (void)in_sizes; (void)n_in; (void)out_size; (void)ws_size;
  const float* x  = (const float*)d_in[0];   // [B,V,N,C] fp32
  const float* wv = (const float*)d_in[1];   // [V,C,C]
  const float* w1 = (const float*)d_in[2];   // [2C,H]
  const float* b1 = (const float*)d_in[3];   // [H]
  const float* w2 = (const float*)d_in[4];   // [H,1]
  // d_in[5] = b2: uniform shift over views -> softmax-invariant, unused.

  unsigned short* ws   = (unsigned short*)d_ws;          // peak ~220 MB (ws ~385 MB)
  unsigned short* wvT  = ws;                             //  2,949,120
  unsigned short* w1aT = ws + 2949120;                   //    589,824
  unsigned short* w1bT = ws + 3538944;                   //    589,824
  unsigned short* xb   = ws + 4128768;                   // 24,084,480  [V,BN,C] bf16
  unsigned short* projb= ws + 28213248;                  // 24,084,480  [V,BN,C]
  unsigned short* xw1b = ws + 52297728;                  // 24,084,480  [V,BN,C]
  unsigned short* pw1b = ws + 76382208;                  // 24,084,480  [V,BN,C]
  unsigned short* cb   = ws + 100466688;                 //  4,816,896  [BN,C]
  unsigned short* cw1  = ws + 105283584;                 //  4,816,896  [BN,C] (in-place per iter)

  float* outc = (float*)d_out;                           // c [B,N,C] fp32
  float* outr = outc + SLAB;                             // r [B,N]   fp32

  k_tr<<<dim3(24, 24, 7), dim3(32, 8), 0, stream>>>(wv, w1, wvT, w1aT, w1bT);
  k_cvt_mean<<<BN_TOT, 192, 0, stream>>>(x, xb, cb);
  // proj_v = x_v @ wv_v ; xw1_v = x_v @ w1[:C]  (one launch, 2940 blocks)
  gemm_bt<0><<<dim3(12, 49, NVIEW), 256, 0, stream>>>(xb, wvT, w1aT, projb, xw1b);
  // pw1b_v = proj_v @ w1b ; cw1_0 = c_0 @ w1b   (one launch, 1764 blocks)
  gemm_bt<1><<<dim3(6, 49, NVIEW + 1), 256, 0, stream>>>(projb, cb, w1bT, pw1b, cw1);
  // iterations: no GEMMs — cw1_{i+1} = sum_v a_v * pw1b_v (linearity of @w1b)
  k_iter<<<BN_TOT, 192, 0, stream>>>(xw1b, cw1, pw1b, b1, w2, outc, outr, 0);
  k_iter<<<BN_TOT, 192, 0, stream>>>(xw1b, cw1, pw1b, b1, w2, outc, outr, 0);
  k_iter<<<BN_TOT, 192, 0, stream>>>(xw1b, cw1, projb, b1, w2, outc, outr, 1);
}